// Round 9
// baseline (130.305 us; speedup 1.0000x reference)
//
#include <hip/hip_runtime.h>

#define N_NODES 40000
#define N_EDGES 640000
#define D_FEAT  128
#define CAP     32        // 32 packed 4B entries per node = one 128B line
#define OCAP    8192      // overflow list capacity (expected ~1 used)
#define NSLICE  8         // row slices == XCD count
#define SLICE_NODES 5000  // N_NODES / NSLICE
#define NSUB    16        // sub-ranges per slice
#define NBIN    (NSLICE * NSUB)        // 128 bins
#define BIN2    56        // per-(bin,block) region capacity (lambda=32, +4.2 sigma)
#define STAGE_BLOCKS 157  // 1024 thr * 4 edges = 4096/block; 157*4096 >= 640000
#define HEAVY_BLOCKS NBIN // 128 consume blocks, one per bin
#define RANGE_MAX 313     // max nodes owned by one consume block
#define SCAN_BLOCK 256
#define N_SCAN_BLOCKS ((N_NODES + SCAN_BLOCK - 1) / SCAN_BLOCK)   // 157

typedef float    f32x4 __attribute__((ext_vector_type(4)));

__device__ __forceinline__ unsigned bf16r(float f) {   // round-to-nearest-even bf16 bits
    unsigned u = __float_as_uint(f);
    return (u + 0x7FFFu + ((u >> 16) & 1u)) >> 16;
}

// ================= Fast path =================
// P1 (stage): 157 blocks x 1024 thr, each edge read EXACTLY ONCE (int4),
//     binned in LDS into 128 bins (lambda=32/bin), flushed COALESCED to
//     fixed per-(bin,block) regions of BIN2=56, sentinel-padded. ZERO
//     global atomics.
// P2 (consume): 128 heavy blocks (1024 thr), one per bin, scans its bin
//     uint4-vectorized, builds cnt/bucket in LDS (41KB), flushes plain
//     stores + full coalesced 128B lines (sole writer per line).
// P3 (gather): reads x DIRECTLY as f32 (no bf16 conversion pass -- R8's
//     conv rider moved 30.7MB of HBM traffic purely to halve gather's
//     L2-resident footprint; sorted lockstep sweep keeps the per-XCD
//     working set ~2.6MB < 4MB L2, so f32 is absorbed by cache).
// All overflows (bin full / deg>CAP) go ONLY to the global overflow list,
// consumed per-node at gather time. ocount = cursors[N_NODES].

__global__ __launch_bounds__(1024) void stage_kernel(
    const int*   __restrict__ rows,
    const int*   __restrict__ cols,
    const float* __restrict__ vals,
    int*          __restrict__ ocount,    // &cursors[N_NODES], zeroed
    int2*         __restrict__ overflow,  // [OCAP] (row, packed)
    uint2*        __restrict__ queue)     // [NBIN*STAGE_BLOCKS*BIN2]
{
    __shared__ int   cnt[NBIN];
    __shared__ uint2 bin[NBIN][BIN2];     // 57.3 KB

    for (int i = threadIdx.x; i < NBIN; i += 1024) cnt[i] = 0;
    __syncthreads();

    int vidx = blockIdx.x * 1024 + threadIdx.x;   // int4 index
    if (vidx < N_EDGES / 4) {                     // last block partial
        int4   r4 = ((const int4*)  rows)[vidx];
        int4   c4 = ((const int4*)  cols)[vidx];
        float4 v4 = ((const float4*)vals)[vidx];
        int    rr[4] = { r4.x, r4.y, r4.z, r4.w };
        int    cc[4] = { c4.x, c4.y, c4.z, c4.w };
        float  vv[4] = { v4.x, v4.y, v4.z, v4.w };

        #pragma unroll
        for (int j = 0; j < 4; ++j) {
            int r = rr[j];
            unsigned p = ((unsigned)cc[j] << 16) | bf16r(vv[j]);
            int sl  = r / SLICE_NODES;                     // 0..7  (magic-mul)
            int lr  = r - sl * SLICE_NODES;                // 0..4999
            int sub = (lr * NSUB) / SLICE_NODES;           // 0..15 (magic-mul)
            int bi  = sl * NSUB + sub;
            int idx = atomicAdd(&cnt[bi], 1);              // LDS, ~32/bin avg
            if (idx < BIN2) {
                bin[bi][idx] = make_uint2(p, (unsigned)r);
            } else {                                       // ~1 grid-wide
                int o = atomicAdd(ocount, 1);
                if (o < OCAP) overflow[o] = make_int2(r, (int)p);
            }
        }
    }
    __syncthreads();

    // flush: fixed region (bi, blockIdx.x), sentinel-pad unused slots (7 iters)
    int b = blockIdx.x;
    for (int idx = threadIdx.x; idx < NBIN * BIN2; idx += 1024) {
        unsigned bi   = (unsigned)idx / BIN2;              // magic-div
        unsigned slot = (unsigned)idx - bi * BIN2;
        int c = min(cnt[bi], BIN2);
        uint2 rec = (slot < (unsigned)c) ? bin[bi][slot]
                                         : make_uint2(0u, 0xFFFFFFFFu);
        queue[((size_t)bi * STAGE_BLOCKS + b) * BIN2 + slot] = rec;
    }
}

__global__ __launch_bounds__(1024) void consume_kernel(
    const uint2* __restrict__ queue,
    int*          __restrict__ cursors,
    unsigned*     __restrict__ bucket,
    int*          __restrict__ ocount,
    int2*         __restrict__ overflow)
{
    int b = blockIdx.x;                   // 128 blocks, one per bin
    int s = b & 7;                        // slice == XCD (dispatch heuristic)
    int j = b >> 3;                       // 0..15 sub-range
    int loc0  = (j * SLICE_NODES + NSUB - 1) / NSUB;        // ceil
    int loc1  = ((j + 1) * SLICE_NODES + NSUB - 1) / NSUB;
    int range = loc1 - loc0;              // 312 or 313
    int node0 = s * SLICE_NODES + loc0;   // absolute first node owned

    __shared__ int      lcnt[RANGE_MAX];
    __shared__ unsigned lbuck[RANGE_MAX][CAP];   // 40.1 KB

    for (int i = threadIdx.x; i < range; i += 1024) lcnt[i] = 0;
    __syncthreads();

    // uint4 scan of this bin: 157*56/2 = 4396 loads, 2 records each
    const uint4* q4 = (const uint4*)(queue + (size_t)(s * NSUB + j) * STAGE_BLOCKS * BIN2);
    const int n4 = STAGE_BLOCKS * BIN2 / 2;        // 4396
    for (int i = threadIdx.x; i < n4; i += 1024) {
        uint4 rec = q4[i];                // coalesced 16B
        unsigned ln0 = rec.y - (unsigned)node0;
        if (ln0 < (unsigned)range) {      // sentinels never match
            int idx = atomicAdd(&lcnt[ln0], 1);         // LDS atomic
            if (idx < CAP) lbuck[ln0][idx] = rec.x;
            else { int o = atomicAdd(ocount, 1);        // rare: deg>32
                   if (o < OCAP) overflow[o] = make_int2((int)rec.y, (int)rec.x); }
        }
        unsigned ln1 = rec.w - (unsigned)node0;
        if (ln1 < (unsigned)range) {
            int idx = atomicAdd(&lcnt[ln1], 1);
            if (idx < CAP) lbuck[ln1][idx] = rec.z;
            else { int o = atomicAdd(ocount, 1);
                   if (o < OCAP) overflow[o] = make_int2((int)rec.w, (int)rec.z); }
        }
    }
    __syncthreads();

    // plain stores: this block is the sole writer of its nodes' lines
    for (int i = threadIdx.x; i < range; i += 1024)
        cursors[node0 + i] = lcnt[i];
    const unsigned* lb = &lbuck[0][0];
    unsigned* gb = bucket + (size_t)node0 * CAP;
    for (int w = threadIdx.x; w < range * CAP; w += 1024)
        gb[w] = lb[w];                    // full 128B lines, coalesced
}

// Gather: one half-wave per node; nodes remapped so the node's bucket slice is
// XCD-local. Entries loaded one-per-lane (coalesced 128B), bitonic-sorted by
// packed value (col in high bits) so ALL waves sweep x low->high in near
// lockstep -> per-XCD L2 working set ~2.6MB (< 4MB L2). f32 x, no conv pass.
__global__ __launch_bounds__(256, 4) void gather_f32_kernel(
    const float*    __restrict__ x,
    const int*      __restrict__ cursors,
    const unsigned* __restrict__ bucket,
    const int2*     __restrict__ overflow,
    const float*    __restrict__ bias,
    float*          __restrict__ out)
{
    int b    = blockIdx.x;            // 5000 blocks
    int hw   = threadIdx.x >> 5;      // 0..7
    int lane = threadIdx.x & 31;
    int node = (b & 7) * SLICE_NODES + (b >> 3) * 8 + hw;   // XCD-local slice

    int k = min(cursors[node], CAP);
    const unsigned* base = bucket + (unsigned)node * CAP;

    // one entry per lane (single coalesced 128B line), pad with 0xFFFFFFFF
    unsigned ent = (lane < k) ? base[lane] : 0xFFFFFFFFu;

    // bitonic sort ascending across the 32-lane half-wave (xor masks <= 16
    // stay within the half). col<40000 => valid entries < 0x9C40FFFF < pad.
    #pragma unroll
    for (int kk = 2; kk <= 32; kk <<= 1) {
        #pragma unroll
        for (int j = kk >> 1; j > 0; j >>= 1) {
            unsigned other = __shfl_xor(ent, j, 64);
            bool up      = ((lane & kk) == 0);
            bool lower   = ((lane & j) == 0);
            unsigned mn  = min(ent, other), mx = max(ent, other);
            ent = (up == lower) ? mn : mx;
        }
    }

    int wb = threadIdx.x & 32;        // shfl base of my half-wave

    float4 acc0 = make_float4(0.f, 0.f, 0.f, 0.f);
    float4 acc1 = make_float4(0.f, 0.f, 0.f, 0.f);
    float  deg  = 0.f;

    // consume a prefetched float4 W_ for packed entry P_ into accumulator A_
    // (param names must not collide with float4 members .x/.y/.z/.w)
    #define ACC(P_, W_, A_)  {                                             \
        float _v = __uint_as_float((P_) << 16);                            \
        deg += _v;                                                         \
        A_.x += _v * (W_).x; A_.y += _v * (W_).y;                          \
        A_.z += _v * (W_).z; A_.w += _v * (W_).w; }

    #define PROC(E_, A_)  {                                                \
        unsigned _en = (E_);                                               \
        float4 _wv = ((const float4*)(x + (size_t)(_en >> 16) * D_FEAT))[lane]; \
        ACC(_en, _wv, A_); }

    int e = 0;
    for (; e + 8 <= k; e += 8) {      // ascending-col order, 8 gathers in flight
        unsigned p0 = __shfl(ent, wb + e,     64);
        unsigned p1 = __shfl(ent, wb + e + 1, 64);
        unsigned p2 = __shfl(ent, wb + e + 2, 64);
        unsigned p3 = __shfl(ent, wb + e + 3, 64);
        unsigned p4 = __shfl(ent, wb + e + 4, 64);
        unsigned p5 = __shfl(ent, wb + e + 5, 64);
        unsigned p6 = __shfl(ent, wb + e + 6, 64);
        unsigned p7 = __shfl(ent, wb + e + 7, 64);
        float4 w0 = ((const float4*)(x + (size_t)(p0 >> 16) * D_FEAT))[lane];
        float4 w1 = ((const float4*)(x + (size_t)(p1 >> 16) * D_FEAT))[lane];
        float4 w2 = ((const float4*)(x + (size_t)(p2 >> 16) * D_FEAT))[lane];
        float4 w3 = ((const float4*)(x + (size_t)(p3 >> 16) * D_FEAT))[lane];
        float4 w4 = ((const float4*)(x + (size_t)(p4 >> 16) * D_FEAT))[lane];
        float4 w5 = ((const float4*)(x + (size_t)(p5 >> 16) * D_FEAT))[lane];
        float4 w6 = ((const float4*)(x + (size_t)(p6 >> 16) * D_FEAT))[lane];
        float4 w7 = ((const float4*)(x + (size_t)(p7 >> 16) * D_FEAT))[lane];
        ACC(p0, w0, acc0); ACC(p1, w1, acc1);
        ACC(p2, w2, acc0); ACC(p3, w3, acc1);
        ACC(p4, w4, acc0); ACC(p5, w5, acc1);
        ACC(p6, w6, acc0); ACC(p7, w7, acc1);
    }
    for (; e + 4 <= k; e += 4) {
        unsigned p0 = __shfl(ent, wb + e,     64);
        unsigned p1 = __shfl(ent, wb + e + 1, 64);
        unsigned p2 = __shfl(ent, wb + e + 2, 64);
        unsigned p3 = __shfl(ent, wb + e + 3, 64);
        float4 w0 = ((const float4*)(x + (size_t)(p0 >> 16) * D_FEAT))[lane];
        float4 w1 = ((const float4*)(x + (size_t)(p1 >> 16) * D_FEAT))[lane];
        float4 w2 = ((const float4*)(x + (size_t)(p2 >> 16) * D_FEAT))[lane];
        float4 w3 = ((const float4*)(x + (size_t)(p3 >> 16) * D_FEAT))[lane];
        ACC(p0, w0, acc0); ACC(p1, w1, acc1);
        ACC(p2, w2, acc0); ACC(p3, w3, acc1);
    }
    for (; e < k; ++e) {
        unsigned p = __shfl(ent, wb + e, 64);
        PROC(p, acc0);
    }

    // Rare overflow entries (ocount==0 in the common case).
    int oc = min(cursors[N_NODES], OCAP);
    for (int i = 0; i < oc; ++i) {
        int2 entv = overflow[i];
        if (entv.x == node) PROC((unsigned)entv.y, acc0);
    }
    #undef PROC
    #undef ACC

    float inv = (deg == 0.f) ? 0.f : 1.f / deg;
    float4 bv = ((const float4*)bias)[lane];
    f32x4 ov;
    ov.x = (acc0.x + acc1.x) * inv + bv.x;
    ov.y = (acc0.y + acc1.y) * inv + bv.y;
    ov.z = (acc0.z + acc1.z) * inv + bv.z;
    ov.w = (acc0.w + acc1.w) * inv + bv.w;
    __builtin_nontemporal_store(ov, (f32x4*)(out + (size_t)node * D_FEAT) + lane);
}

// ================= CSR middle path (general fallback, f32) =================

__global__ __launch_bounds__(256) void histogram_kernel(
    const int* __restrict__ rows, int* __restrict__ counts)
{
    int e = blockIdx.x * blockDim.x + threadIdx.x;
    if (e < N_EDGES) atomicAdd(&counts[rows[e]], 1);
}

__global__ __launch_bounds__(SCAN_BLOCK) void scan1_kernel(
    const int* __restrict__ counts, int* __restrict__ offsets, int* __restrict__ blocksums)
{
    __shared__ int tmp[SCAN_BLOCK];
    int t = threadIdx.x;
    int g = blockIdx.x * SCAN_BLOCK + t;
    int v = (g < N_NODES) ? counts[g] : 0;
    tmp[t] = v;
    __syncthreads();
    #pragma unroll
    for (int off = 1; off < SCAN_BLOCK; off <<= 1) {
        int add = (t >= off) ? tmp[t - off] : 0;
        __syncthreads();
        tmp[t] += add;
        __syncthreads();
    }
    if (g < N_NODES) offsets[g] = tmp[t] - v;
    if (t == SCAN_BLOCK - 1) blocksums[blockIdx.x] = tmp[t];
}

__global__ __launch_bounds__(SCAN_BLOCK) void scan2_kernel(int* __restrict__ blocksums)
{
    __shared__ int tmp[SCAN_BLOCK];
    int t = threadIdx.x;
    int v = (t < N_SCAN_BLOCKS) ? blocksums[t] : 0;
    tmp[t] = v;
    __syncthreads();
    #pragma unroll
    for (int off = 1; off < SCAN_BLOCK; off <<= 1) {
        int add = (t >= off) ? tmp[t - off] : 0;
        __syncthreads();
        tmp[t] += add;
        __syncthreads();
    }
    if (t < N_SCAN_BLOCKS) blocksums[t] = tmp[t] - v;
}

__global__ __launch_bounds__(SCAN_BLOCK) void scan3_kernel(
    int* __restrict__ offsets, int* __restrict__ cursors, const int* __restrict__ blocksums)
{
    int t = threadIdx.x;
    int g = blockIdx.x * SCAN_BLOCK + t;
    if (g < N_NODES) {
        int o = offsets[g] + blocksums[blockIdx.x];
        offsets[g] = o;
        cursors[g] = o;
    }
    if (g == 0) offsets[N_NODES] = N_EDGES;
}

__global__ __launch_bounds__(256) void bucket_kernel(
    const int* __restrict__ rows, const int* __restrict__ cols,
    const float* __restrict__ vals, int* __restrict__ cursors, int2* __restrict__ bucket)
{
    int e = blockIdx.x * blockDim.x + threadIdx.x;
    if (e >= N_EDGES) return;
    int r = rows[e];
    int pos = atomicAdd(&cursors[r], 1);
    bucket[pos] = make_int2(cols[e], __float_as_int(vals[e]));
}

__global__ __launch_bounds__(256) void gather_csr_kernel(
    const float* __restrict__ x, const int* __restrict__ offsets,
    const int2* __restrict__ bucket, const float* __restrict__ bias,
    float* __restrict__ out)
{
    int t = blockIdx.x * blockDim.x + threadIdx.x;
    int node = t >> 5;
    if (node >= N_NODES) return;
    int lane = t & 31;
    int beg = offsets[node];
    int end = offsets[node + 1];
    float4 acc = make_float4(0.f, 0.f, 0.f, 0.f);
    float deg = 0.f;
    int2 ent = (beg < end) ? bucket[beg] : make_int2(0, 0);
    for (int e = beg; e < end; ++e) {
        int2 cur = ent;
        if (e + 1 < end) ent = bucket[e + 1];
        float v = __int_as_float(cur.y);
        deg += v;
        float4 xv = ((const float4*)(x + (size_t)cur.x * D_FEAT))[lane];
        acc.x += v * xv.x; acc.y += v * xv.y; acc.z += v * xv.z; acc.w += v * xv.w;
    }
    float inv = (deg == 0.f) ? 0.f : 1.f / deg;
    float4 bv = ((const float4*)bias)[lane];
    float4 ov;
    ov.x = acc.x * inv + bv.x; ov.y = acc.y * inv + bv.y;
    ov.z = acc.z * inv + bv.z; ov.w = acc.w * inv + bv.w;
    ((float4*)(out + (size_t)node * D_FEAT))[lane] = ov;
}

// ================= Atomic fallback =================

__global__ __launch_bounds__(256) void edge_scatter_kernel(
    const float* __restrict__ x, const int* __restrict__ rows,
    const int* __restrict__ cols, const float* __restrict__ vals,
    float* __restrict__ agg, float* __restrict__ deg)
{
    int t = blockIdx.x * blockDim.x + threadIdx.x;
    int edge = t >> 5;
    if (edge >= N_EDGES) return;
    int lane = t & 31;
    int row = rows[edge]; int col = cols[edge]; float v = vals[edge];
    float4 xv = ((const float4*)(x + (size_t)col * D_FEAT))[lane];
    float* dst = agg + (size_t)row * D_FEAT + lane * 4;
    unsafeAtomicAdd(dst + 0, v * xv.x);
    unsafeAtomicAdd(dst + 1, v * xv.y);
    unsafeAtomicAdd(dst + 2, v * xv.z);
    unsafeAtomicAdd(dst + 3, v * xv.w);
    if (lane == 0) unsafeAtomicAdd(deg + row, v);
}

__global__ __launch_bounds__(256) void finalize_kernel(
    float* __restrict__ out, const float* __restrict__ deg, const float* __restrict__ bias)
{
    int t = blockIdx.x * blockDim.x + threadIdx.x;
    int node = t >> 5;
    if (node >= N_NODES) return;
    int lane = t & 31;
    float d = deg[node];
    float inv = (d == 0.f) ? 0.f : 1.f / d;
    float4* o = (float4*)(out + (size_t)node * D_FEAT) + lane;
    float4 bv = ((const float4*)bias)[lane];
    float4 ov = *o;
    ov.x = ov.x * inv + bv.x; ov.y = ov.y * inv + bv.y;
    ov.z = ov.z * inv + bv.z; ov.w = ov.w * inv + bv.w;
    *o = ov;
}

// ================= launch =================

extern "C" void kernel_launch(void* const* d_in, const int* in_sizes, int n_in,
                              void* d_out, int out_size, void* d_ws, size_t ws_size,
                              hipStream_t stream) {
    const float* x    = (const float*)d_in[0];
    const int*   rows = (const int*)  d_in[1];
    const int*   cols = (const int*)  d_in[2];
    const float* vals = (const float*)d_in[3];
    const float* bias = (const float*)d_in[4];
    float* out = (float*)d_out;

    // Fast-path layout (bytes):
    //   cursors  @ 0          ((N_NODES+1)*4 = 160,004; ocount = cursors[N_NODES] @160,000)
    //   overflow @ 160,128    (OCAP * 8 = 65,536)
    //   bucket   @ 225,792    (N_NODES*CAP*4 = 5,120,000)       [128B aligned]
    //   queue    @ 5,345,792  (NBIN*STAGE_BLOCKS*BIN2*8 = 9,003,008)
    char* wb = (char*)d_ws;
    int*      f_cursors  = (int*)     wb;
    int*      f_ocount   = (int*)    (wb + (size_t)N_NODES * 4);
    int2*     f_overflow = (int2*)   (wb + 160128);
    unsigned* f_bucket   = (unsigned*)(wb + 225792);
    uint2*    f_queue    = (uint2*)  (wb + 5345792);
    size_t need_fast = 5345792 + (size_t)NBIN * STAGE_BLOCKS * BIN2 * 8;  // ~14.3 MB

    // CSR-path layout (ints): counts | offsets@40064 | cursors@80128 | blocksums@120128 | bucket@120448
    int* w = (int*)d_ws;
    size_t need_csr = ((size_t)120448 + 2u * N_EDGES) * sizeof(int);   // ~5.6 MB

    if (ws_size >= need_fast) {
        (void)hipMemsetAsync(f_ocount, 0, 4, stream);   // only the overflow count
        stage_kernel<<<STAGE_BLOCKS, 1024, 0, stream>>>(
            rows, cols, vals, f_ocount, f_overflow, f_queue);
        consume_kernel<<<HEAVY_BLOCKS, 1024, 0, stream>>>(
            f_queue, f_cursors, f_bucket, f_ocount, f_overflow);
        gather_f32_kernel<<<N_NODES / 8, 256, 0, stream>>>(
            x, f_cursors, f_bucket, f_overflow, bias, out);
    } else if (ws_size >= need_csr) {
        int*  counts    = w;
        int*  offsets   = w + 40064;
        int*  cursors   = w + 80128;
        int*  blocksums = w + 120128;
        int2* bucket    = (int2*)(w + 120448);
        (void)hipMemsetAsync(counts, 0, N_NODES * sizeof(int), stream);
        histogram_kernel<<<(N_EDGES + 255) / 256, 256, 0, stream>>>(rows, counts);
        scan1_kernel<<<N_SCAN_BLOCKS, SCAN_BLOCK, 0, stream>>>(counts, offsets, blocksums);
        scan2_kernel<<<1, SCAN_BLOCK, 0, stream>>>(blocksums);
        scan3_kernel<<<N_SCAN_BLOCKS, SCAN_BLOCK, 0, stream>>>(offsets, cursors, blocksums);
        bucket_kernel<<<(N_EDGES + 255) / 256, 256, 0, stream>>>(rows, cols, vals, cursors, bucket);
        int threads = N_NODES * 32;
        gather_csr_kernel<<<(threads + 255) / 256, 256, 0, stream>>>(x, offsets, bucket, bias, out);
    } else {
        float* deg = (float*)d_ws;
        (void)hipMemsetAsync(out, 0, (size_t)N_NODES * D_FEAT * sizeof(float), stream);
        (void)hipMemsetAsync(deg, 0, (size_t)N_NODES * sizeof(float), stream);
        int et = N_EDGES * 32;
        edge_scatter_kernel<<<(et + 255) / 256, 256, 0, stream>>>(x, rows, cols, vals, out, deg);
        int nt = N_NODES * 32;
        finalize_kernel<<<(nt + 255) / 256, 256, 0, stream>>>(out, deg, bias);
    }
}

// Round 10
// 114.633 us; speedup vs baseline: 1.1367x; 1.1367x over previous
//
#include <hip/hip_runtime.h>

#define N_NODES 40000
#define N_EDGES 640000
#define D_FEAT  128
#define CAP     32        // 32 packed 4B entries per node = one 128B line
#define OCAP    8192      // overflow list capacity (expected ~1 used)
#define NSLICE  8         // row slices == XCD count
#define SLICE_NODES 5000  // N_NODES / NSLICE
#define NSUB    16        // sub-ranges per slice
#define NBIN    (NSLICE * NSUB)        // 128 bins
#define BIN2    56        // per-(bin,block) region capacity (lambda=32, +4.2 sigma)
#define STAGE_BLOCKS 157  // 1024 thr * 4 edges = 4096/block; 157*4096 >= 640000
#define REGION  (STAGE_BLOCKS * BIN2)  // 8792 records per bin
#define HEAVY_BLOCKS NBIN // 128 consume blocks, one per bin
#define CONV_BLOCKS_1K 1250   // 1250*1024 threads * 4 floats = 5.12M
#define RANGE_MAX 313     // max nodes owned by one consume block
#define SCAN_BLOCK 256
#define N_SCAN_BLOCKS ((N_NODES + SCAN_BLOCK - 1) / SCAN_BLOCK)   // 157

typedef float    f32x4 __attribute__((ext_vector_type(4)));

__device__ __forceinline__ unsigned bf16r(float f) {   // round-to-nearest-even bf16 bits
    unsigned u = __float_as_uint(f);
    return (u + 0x7FFFu + ((u >> 16) & 1u)) >> 16;
}

// ================= Fast path =================
// P1 (stage): 157 blocks x 1024 thr, each edge read EXACTLY ONCE (int4),
//     binned in LDS into 128 bins (lambda=32/bin), flushed COALESCED to
//     fixed per-(bin,block) regions of BIN2=56, sentinel-padded. ZERO
//     global atomics. Queue is SPLIT 6B/record: u32 packed + u16 row-local
//     (row fits 9 bits within a bin) -> 13.5MB round-trip vs R8's 18MB.
// P2 (consume): 128 heavy blocks (1024 thr), one per bin, scans its bin
//     4-records-per-load, builds cnt/bucket in LDS (41KB), flushes plain
//     stores + full coalesced 128B lines (sole writer per line).
//     x->bf16 conv rides along on 1250 other blocks.
// P3 (gather): bf16 xbf reads. (R9 PROVED f32 direct gather thrashes:
//     FETCH 131.8MB, 45us -- the 20.5MB f32 table replicated into all 8
//     private L2s exceeds the 4MB window; bf16's 10.2MB fits. The 30.7MB
//     conv pass buys a ~43us gather saving. Keep bf16.)
// All overflows (bin full / deg>CAP) go ONLY to the global overflow list,
// consumed per-node at gather time. ocount = cursors[N_NODES].

__global__ __launch_bounds__(1024) void stage_kernel(
    const int*   __restrict__ rows,
    const int*   __restrict__ cols,
    const float* __restrict__ vals,
    int*          __restrict__ ocount,    // &cursors[N_NODES], zeroed
    int2*         __restrict__ overflow,  // [OCAP] (row, packed)
    unsigned*       __restrict__ queue_p, // [NBIN*REGION] packed (col<<16|bf16)
    unsigned short* __restrict__ queue_r) // [NBIN*REGION] row-local, 0xFFFF pad
{
    __shared__ int            cnt[NBIN];
    __shared__ unsigned       bin_p[NBIN][BIN2];   // 28.7 KB
    __shared__ unsigned short bin_r[NBIN][BIN2];   // 14.3 KB

    for (int i = threadIdx.x; i < NBIN; i += 1024) cnt[i] = 0;
    __syncthreads();

    int vidx = blockIdx.x * 1024 + threadIdx.x;   // int4 index
    if (vidx < N_EDGES / 4) {                     // last block partial
        int4   r4 = ((const int4*)  rows)[vidx];
        int4   c4 = ((const int4*)  cols)[vidx];
        float4 v4 = ((const float4*)vals)[vidx];
        int    rr[4] = { r4.x, r4.y, r4.z, r4.w };
        int    cc[4] = { c4.x, c4.y, c4.z, c4.w };
        float  vv[4] = { v4.x, v4.y, v4.z, v4.w };

        #pragma unroll
        for (int j = 0; j < 4; ++j) {
            int r = rr[j];
            unsigned p = ((unsigned)cc[j] << 16) | bf16r(vv[j]);
            int sl   = r / SLICE_NODES;                    // 0..7  (magic-mul)
            int lr   = r - sl * SLICE_NODES;               // 0..4999
            int sub  = (lr * NSUB) / SLICE_NODES;          // 0..15 (magic-mul)
            int loc0 = (sub * SLICE_NODES + NSUB - 1) / NSUB;   // bin's first local node
            int bi   = sl * NSUB + sub;
            int idx  = atomicAdd(&cnt[bi], 1);             // LDS, ~32/bin avg
            if (idx < BIN2) {
                bin_p[bi][idx] = p;
                bin_r[bi][idx] = (unsigned short)(lr - loc0);   // 0..312
            } else {                                       // ~1 grid-wide
                int o = atomicAdd(ocount, 1);
                if (o < OCAP) overflow[o] = make_int2(r, (int)p);
            }
        }
    }
    __syncthreads();

    // flush: fixed region (bi, blockIdx.x), sentinel-pad unused slots
    int b = blockIdx.x;
    for (int idx = threadIdx.x; idx < NBIN * BIN2; idx += 1024) {     // 7 iters
        unsigned bi   = (unsigned)idx / BIN2;              // magic-div
        unsigned slot = (unsigned)idx - bi * BIN2;
        int c = min(cnt[bi], BIN2);
        bool v = slot < (unsigned)c;
        size_t g = ((size_t)bi * STAGE_BLOCKS + b) * BIN2 + slot;
        queue_p[g] = v ? bin_p[bi][slot] : 0u;
        queue_r[g] = v ? bin_r[bi][slot] : (unsigned short)0xFFFFu;
    }
}

__global__ __launch_bounds__(1024) void consume_kernel(
    const float*          __restrict__ x,
    const unsigned*       __restrict__ queue_p,
    const unsigned short* __restrict__ queue_r,
    int*          __restrict__ cursors,
    unsigned*     __restrict__ bucket,
    int*          __restrict__ ocount,
    int2*         __restrict__ overflow,
    uint2*        __restrict__ xbf)
{
    int b = blockIdx.x;
    if (b < HEAVY_BLOCKS) {
        int s = b & 7;                        // slice == XCD (dispatch heuristic)
        int j = b >> 3;                       // 0..15 sub-range
        int loc0  = (j * SLICE_NODES + NSUB - 1) / NSUB;        // ceil
        int loc1  = ((j + 1) * SLICE_NODES + NSUB - 1) / NSUB;
        int range = loc1 - loc0;              // 312 or 313
        int node0 = s * SLICE_NODES + loc0;   // absolute first node owned

        __shared__ int      lcnt[RANGE_MAX];
        __shared__ unsigned lbuck[RANGE_MAX][CAP];   // 40.1 KB

        for (int i = threadIdx.x; i < range; i += 1024) lcnt[i] = 0;
        __syncthreads();

        // 4-record scan: 8792/4 = 2198 loads of {uint4 packed, uint2 rowloc}
        int bin = s * NSUB + j;
        const uint4* qp4 = (const uint4*)(queue_p + (size_t)bin * REGION);
        const uint2* qr2 = (const uint2*)(queue_r + (size_t)bin * REGION);
        const int n4 = REGION / 4;            // 2198
        for (int i = threadIdx.x; i < n4; i += 1024) {
            uint4 p4 = qp4[i];                // coalesced 16B
            uint2 r2 = qr2[i];                // coalesced 8B
            unsigned pk[4] = { p4.x, p4.y, p4.z, p4.w };
            unsigned ln[4] = { r2.x & 0xFFFFu, r2.x >> 16,
                               r2.y & 0xFFFFu, r2.y >> 16 };
            #pragma unroll
            for (int t = 0; t < 4; ++t) {
                if (ln[t] < (unsigned)range) {            // 0xFFFF pad fails
                    int idx = atomicAdd(&lcnt[ln[t]], 1); // LDS atomic
                    if (idx < CAP) lbuck[ln[t]][idx] = pk[t];
                    else { int o = atomicAdd(ocount, 1);  // rare: deg>32
                           if (o < OCAP) overflow[o] =
                               make_int2(node0 + (int)ln[t], (int)pk[t]); }
                }
            }
        }
        __syncthreads();

        // plain stores: this block is the sole writer of its nodes' lines
        for (int i = threadIdx.x; i < range; i += 1024)
            cursors[node0 + i] = lcnt[i];
        const unsigned* lb = &lbuck[0][0];
        unsigned* gb = bucket + (size_t)node0 * CAP;
        for (int w = threadIdx.x; w < range * CAP; w += 1024)
            gb[w] = lb[w];                    // full 128B lines, coalesced
        return;
    }
    // conv rider
    int idx = (b - HEAVY_BLOCKS) * 1024 + threadIdx.x;   // < 1,280,000 exactly
    float4 f = ((const float4*)x)[idx];
    uint2 o;
    o.x = bf16r(f.x) | (bf16r(f.y) << 16);
    o.y = bf16r(f.z) | (bf16r(f.w) << 16);
    xbf[idx] = o;
}

// Gather: one half-wave per node; nodes remapped so the node's bucket slice is
// XCD-local. Entries loaded one-per-lane (coalesced 128B), bitonic-sorted by
// packed value (col in high bits) so ALL waves sweep xbf low->high in near
// lockstep -> per-XCD L2 working set small. (~2-3us, near floor.)
__global__ __launch_bounds__(256, 8) void gather_bf_kernel(
    const uint2*    __restrict__ xbf,
    const int*      __restrict__ cursors,
    const unsigned* __restrict__ bucket,
    const int2*     __restrict__ overflow,
    const float*    __restrict__ bias,
    float*          __restrict__ out)
{
    int b    = blockIdx.x;            // 5000 blocks
    int hw   = threadIdx.x >> 5;      // 0..7
    int lane = threadIdx.x & 31;
    int node = (b & 7) * SLICE_NODES + (b >> 3) * 8 + hw;   // XCD-local slice

    int k = min(cursors[node], CAP);
    const unsigned* base = bucket + (unsigned)node * CAP;

    // one entry per lane (single coalesced 128B line), pad with 0xFFFFFFFF
    unsigned ent = (lane < k) ? base[lane] : 0xFFFFFFFFu;

    // bitonic sort ascending across the 32-lane half-wave (xor masks <= 16
    // stay within the half). col<40000 => valid entries < 0x9C40FFFF < pad.
    #pragma unroll
    for (int kk = 2; kk <= 32; kk <<= 1) {
        #pragma unroll
        for (int j = kk >> 1; j > 0; j >>= 1) {
            unsigned other = __shfl_xor(ent, j, 64);
            bool up      = ((lane & kk) == 0);
            bool lower   = ((lane & j) == 0);
            unsigned mn  = min(ent, other), mx = max(ent, other);
            ent = (up == lower) ? mn : mx;
        }
    }

    int wb = threadIdx.x & 32;        // shfl base of my half-wave

    float4 acc0 = make_float4(0.f, 0.f, 0.f, 0.f);
    float4 acc1 = make_float4(0.f, 0.f, 0.f, 0.f);
    float  deg  = 0.f;

    // consume a prefetched word W_ for packed entry P_ into accumulator A_
    // (param names must not collide with float4 members .x/.y/.z/.w)
    #define ACC(P_, W_, A_)  {                                             \
        float _v = __uint_as_float((P_) << 16);                            \
        float _f0 = __uint_as_float((W_).x << 16);                         \
        float _f1 = __uint_as_float((W_).x & 0xFFFF0000u);                 \
        float _f2 = __uint_as_float((W_).y << 16);                         \
        float _f3 = __uint_as_float((W_).y & 0xFFFF0000u);                 \
        deg += _v;                                                         \
        A_.x += _v * _f0; A_.y += _v * _f1;                                \
        A_.z += _v * _f2; A_.w += _v * _f3; }

    #define PROC(E_, A_)  {                                                \
        unsigned _en = (E_);                                               \
        uint2 _wv = xbf[(_en >> 16) * 32u + (unsigned)lane];               \
        ACC(_en, _wv, A_); }

    int e = 0;
    for (; e + 8 <= k; e += 8) {      // ascending-col order, 8 gathers in flight
        unsigned p0 = __shfl(ent, wb + e,     64);
        unsigned p1 = __shfl(ent, wb + e + 1, 64);
        unsigned p2 = __shfl(ent, wb + e + 2, 64);
        unsigned p3 = __shfl(ent, wb + e + 3, 64);
        unsigned p4 = __shfl(ent, wb + e + 4, 64);
        unsigned p5 = __shfl(ent, wb + e + 5, 64);
        unsigned p6 = __shfl(ent, wb + e + 6, 64);
        unsigned p7 = __shfl(ent, wb + e + 7, 64);
        uint2 w0 = xbf[(p0 >> 16) * 32u + (unsigned)lane];
        uint2 w1 = xbf[(p1 >> 16) * 32u + (unsigned)lane];
        uint2 w2 = xbf[(p2 >> 16) * 32u + (unsigned)lane];
        uint2 w3 = xbf[(p3 >> 16) * 32u + (unsigned)lane];
        uint2 w4 = xbf[(p4 >> 16) * 32u + (unsigned)lane];
        uint2 w5 = xbf[(p5 >> 16) * 32u + (unsigned)lane];
        uint2 w6 = xbf[(p6 >> 16) * 32u + (unsigned)lane];
        uint2 w7 = xbf[(p7 >> 16) * 32u + (unsigned)lane];
        ACC(p0, w0, acc0); ACC(p1, w1, acc1);
        ACC(p2, w2, acc0); ACC(p3, w3, acc1);
        ACC(p4, w4, acc0); ACC(p5, w5, acc1);
        ACC(p6, w6, acc0); ACC(p7, w7, acc1);
    }
    for (; e + 4 <= k; e += 4) {
        unsigned p0 = __shfl(ent, wb + e,     64);
        unsigned p1 = __shfl(ent, wb + e + 1, 64);
        unsigned p2 = __shfl(ent, wb + e + 2, 64);
        unsigned p3 = __shfl(ent, wb + e + 3, 64);
        uint2 w0 = xbf[(p0 >> 16) * 32u + (unsigned)lane];
        uint2 w1 = xbf[(p1 >> 16) * 32u + (unsigned)lane];
        uint2 w2 = xbf[(p2 >> 16) * 32u + (unsigned)lane];
        uint2 w3 = xbf[(p3 >> 16) * 32u + (unsigned)lane];
        ACC(p0, w0, acc0); ACC(p1, w1, acc1);
        ACC(p2, w2, acc0); ACC(p3, w3, acc1);
    }
    for (; e < k; ++e) {
        unsigned p = __shfl(ent, wb + e, 64);
        PROC(p, acc0);
    }

    // Rare overflow entries (ocount==0 in the common case).
    int oc = min(cursors[N_NODES], OCAP);
    for (int i = 0; i < oc; ++i) {
        int2 entv = overflow[i];
        if (entv.x == node) PROC((unsigned)entv.y, acc0);
    }
    #undef PROC
    #undef ACC

    float inv = (deg == 0.f) ? 0.f : 1.f / deg;
    float4 bv = ((const float4*)bias)[lane];
    f32x4 ov;
    ov.x = (acc0.x + acc1.x) * inv + bv.x;
    ov.y = (acc0.y + acc1.y) * inv + bv.y;
    ov.z = (acc0.z + acc1.z) * inv + bv.z;
    ov.w = (acc0.w + acc1.w) * inv + bv.w;
    __builtin_nontemporal_store(ov, (f32x4*)(out + (size_t)node * D_FEAT) + lane);
}

// ================= CSR middle path (general fallback, f32) =================

__global__ __launch_bounds__(256) void histogram_kernel(
    const int* __restrict__ rows, int* __restrict__ counts)
{
    int e = blockIdx.x * blockDim.x + threadIdx.x;
    if (e < N_EDGES) atomicAdd(&counts[rows[e]], 1);
}

__global__ __launch_bounds__(SCAN_BLOCK) void scan1_kernel(
    const int* __restrict__ counts, int* __restrict__ offsets, int* __restrict__ blocksums)
{
    __shared__ int tmp[SCAN_BLOCK];
    int t = threadIdx.x;
    int g = blockIdx.x * SCAN_BLOCK + t;
    int v = (g < N_NODES) ? counts[g] : 0;
    tmp[t] = v;
    __syncthreads();
    #pragma unroll
    for (int off = 1; off < SCAN_BLOCK; off <<= 1) {
        int add = (t >= off) ? tmp[t - off] : 0;
        __syncthreads();
        tmp[t] += add;
        __syncthreads();
    }
    if (g < N_NODES) offsets[g] = tmp[t] - v;
    if (t == SCAN_BLOCK - 1) blocksums[blockIdx.x] = tmp[t];
}

__global__ __launch_bounds__(SCAN_BLOCK) void scan2_kernel(int* __restrict__ blocksums)
{
    __shared__ int tmp[SCAN_BLOCK];
    int t = threadIdx.x;
    int v = (t < N_SCAN_BLOCKS) ? blocksums[t] : 0;
    tmp[t] = v;
    __syncthreads();
    #pragma unroll
    for (int off = 1; off < SCAN_BLOCK; off <<= 1) {
        int add = (t >= off) ? tmp[t - off] : 0;
        __syncthreads();
        tmp[t] += add;
        __syncthreads();
    }
    if (t < N_SCAN_BLOCKS) blocksums[t] = tmp[t] - v;
}

__global__ __launch_bounds__(SCAN_BLOCK) void scan3_kernel(
    int* __restrict__ offsets, int* __restrict__ cursors, const int* __restrict__ blocksums)
{
    int t = threadIdx.x;
    int g = blockIdx.x * SCAN_BLOCK + t;
    if (g < N_NODES) {
        int o = offsets[g] + blocksums[blockIdx.x];
        offsets[g] = o;
        cursors[g] = o;
    }
    if (g == 0) offsets[N_NODES] = N_EDGES;
}

__global__ __launch_bounds__(256) void bucket_kernel(
    const int* __restrict__ rows, const int* __restrict__ cols,
    const float* __restrict__ vals, int* __restrict__ cursors, int2* __restrict__ bucket)
{
    int e = blockIdx.x * blockDim.x + threadIdx.x;
    if (e >= N_EDGES) return;
    int r = rows[e];
    int pos = atomicAdd(&cursors[r], 1);
    bucket[pos] = make_int2(cols[e], __float_as_int(vals[e]));
}

__global__ __launch_bounds__(256) void gather_csr_kernel(
    const float* __restrict__ x, const int* __restrict__ offsets,
    const int2* __restrict__ bucket, const float* __restrict__ bias,
    float* __restrict__ out)
{
    int t = blockIdx.x * blockDim.x + threadIdx.x;
    int node = t >> 5;
    if (node >= N_NODES) return;
    int lane = t & 31;
    int beg = offsets[node];
    int end = offsets[node + 1];
    float4 acc = make_float4(0.f, 0.f, 0.f, 0.f);
    float deg = 0.f;
    int2 ent = (beg < end) ? bucket[beg] : make_int2(0, 0);
    for (int e = beg; e < end; ++e) {
        int2 cur = ent;
        if (e + 1 < end) ent = bucket[e + 1];
        float v = __int_as_float(cur.y);
        deg += v;
        float4 xv = ((const float4*)(x + (size_t)cur.x * D_FEAT))[lane];
        acc.x += v * xv.x; acc.y += v * xv.y; acc.z += v * xv.z; acc.w += v * xv.w;
    }
    float inv = (deg == 0.f) ? 0.f : 1.f / deg;
    float4 bv = ((const float4*)bias)[lane];
    float4 ov;
    ov.x = acc.x * inv + bv.x; ov.y = acc.y * inv + bv.y;
    ov.z = acc.z * inv + bv.z; ov.w = acc.w * inv + bv.w;
    ((float4*)(out + (size_t)node * D_FEAT))[lane] = ov;
}

// ================= Atomic fallback =================

__global__ __launch_bounds__(256) void edge_scatter_kernel(
    const float* __restrict__ x, const int* __restrict__ rows,
    const int* __restrict__ cols, const float* __restrict__ vals,
    float* __restrict__ agg, float* __restrict__ deg)
{
    int t = blockIdx.x * blockDim.x + threadIdx.x;
    int edge = t >> 5;
    if (edge >= N_EDGES) return;
    int lane = t & 31;
    int row = rows[edge]; int col = cols[edge]; float v = vals[edge];
    float4 xv = ((const float4*)(x + (size_t)col * D_FEAT))[lane];
    float* dst = agg + (size_t)row * D_FEAT + lane * 4;
    unsafeAtomicAdd(dst + 0, v * xv.x);
    unsafeAtomicAdd(dst + 1, v * xv.y);
    unsafeAtomicAdd(dst + 2, v * xv.z);
    unsafeAtomicAdd(dst + 3, v * xv.w);
    if (lane == 0) unsafeAtomicAdd(deg + row, v);
}

__global__ __launch_bounds__(256) void finalize_kernel(
    float* __restrict__ out, const float* __restrict__ deg, const float* __restrict__ bias)
{
    int t = blockIdx.x * blockDim.x + threadIdx.x;
    int node = t >> 5;
    if (node >= N_NODES) return;
    int lane = t & 31;
    float d = deg[node];
    float inv = (d == 0.f) ? 0.f : 1.f / d;
    float4* o = (float4*)(out + (size_t)node * D_FEAT) + lane;
    float4 bv = ((const float4*)bias)[lane];
    float4 ov = *o;
    ov.x = ov.x * inv + bv.x; ov.y = ov.y * inv + bv.y;
    ov.z = ov.z * inv + bv.z; ov.w = ov.w * inv + bv.w;
    *o = ov;
}

// ================= launch =================

extern "C" void kernel_launch(void* const* d_in, const int* in_sizes, int n_in,
                              void* d_out, int out_size, void* d_ws, size_t ws_size,
                              hipStream_t stream) {
    const float* x    = (const float*)d_in[0];
    const int*   rows = (const int*)  d_in[1];
    const int*   cols = (const int*)  d_in[2];
    const float* vals = (const float*)d_in[3];
    const float* bias = (const float*)d_in[4];
    float* out = (float*)d_out;

    // Fast-path layout (bytes):
    //   cursors  @ 0          ((N_NODES+1)*4 = 160,004; ocount = cursors[N_NODES] @160,000)
    //   overflow @ 160,128    (OCAP * 8 = 65,536)
    //   x_bf     @ 225,792    (N_NODES*D_FEAT*2 = 10,240,000)   [128B aligned]
    //   bucket   @ 10,465,792 (N_NODES*CAP*4 = 5,120,000)       [128B aligned]
    //   queue_p  @ 15,585,792 (NBIN*REGION*4 = 4,501,504)       [128B aligned]
    //   queue_r  @ 20,087,296 (NBIN*REGION*2 = 2,250,752)       [128B aligned]
    char* wb = (char*)d_ws;
    int*            f_cursors  = (int*)     wb;
    int*            f_ocount   = (int*)    (wb + (size_t)N_NODES * 4);
    int2*           f_overflow = (int2*)   (wb + 160128);
    uint2*          f_xbf      = (uint2*)  (wb + 225792);
    unsigned*       f_bucket   = (unsigned*)(wb + 10465792);
    unsigned*       f_queue_p  = (unsigned*)(wb + 15585792);
    unsigned short* f_queue_r  = (unsigned short*)(wb + 20087296);
    size_t need_fast = 20087296 + (size_t)NBIN * REGION * 2;   // ~22.3 MB

    // CSR-path layout (ints): counts | offsets@40064 | cursors@80128 | blocksums@120128 | bucket@120448
    int* w = (int*)d_ws;
    size_t need_csr = ((size_t)120448 + 2u * N_EDGES) * sizeof(int);   // ~5.6 MB

    if (ws_size >= need_fast) {
        (void)hipMemsetAsync(f_ocount, 0, 4, stream);   // only the overflow count
        stage_kernel<<<STAGE_BLOCKS, 1024, 0, stream>>>(
            rows, cols, vals, f_ocount, f_overflow, f_queue_p, f_queue_r);
        consume_kernel<<<HEAVY_BLOCKS + CONV_BLOCKS_1K, 1024, 0, stream>>>(
            x, f_queue_p, f_queue_r, f_cursors, f_bucket, f_ocount, f_overflow, f_xbf);
        gather_bf_kernel<<<N_NODES / 8, 256, 0, stream>>>(
            f_xbf, f_cursors, f_bucket, f_overflow, bias, out);
    } else if (ws_size >= need_csr) {
        int*  counts    = w;
        int*  offsets   = w + 40064;
        int*  cursors   = w + 80128;
        int*  blocksums = w + 120128;
        int2* bucket    = (int2*)(w + 120448);
        (void)hipMemsetAsync(counts, 0, N_NODES * sizeof(int), stream);
        histogram_kernel<<<(N_EDGES + 255) / 256, 256, 0, stream>>>(rows, counts);
        scan1_kernel<<<N_SCAN_BLOCKS, SCAN_BLOCK, 0, stream>>>(counts, offsets, blocksums);
        scan2_kernel<<<1, SCAN_BLOCK, 0, stream>>>(blocksums);
        scan3_kernel<<<N_SCAN_BLOCKS, SCAN_BLOCK, 0, stream>>>(offsets, cursors, blocksums);
        bucket_kernel<<<(N_EDGES + 255) / 256, 256, 0, stream>>>(rows, cols, vals, cursors, bucket);
        int threads = N_NODES * 32;
        gather_csr_kernel<<<(threads + 255) / 256, 256, 0, stream>>>(x, offsets, bucket, bias, out);
    } else {
        float* deg = (float*)d_ws;
        (void)hipMemsetAsync(out, 0, (size_t)N_NODES * D_FEAT * sizeof(float), stream);
        (void)hipMemsetAsync(deg, 0, (size_t)N_NODES * sizeof(float), stream);
        int et = N_EDGES * 32;
        edge_scatter_kernel<<<(et + 255) / 256, 256, 0, stream>>>(x, rows, cols, vals, out, deg);
        int nt = N_NODES * 32;
        finalize_kernel<<<(nt + 255) / 256, 256, 0, stream>>>(out, deg, bias);
    }
}